// Round 10
// baseline (222.452 us; speedup 1.0000x reference)
//
#include <hip/hip_runtime.h>
#include <hip/hip_bf16.h>

// ---------------------------------------------------------------------------
// Conv2DKAN: out[b,ho,wo,f] = sum_{di,dj,c,k} feat(x[b,ho+di,wo+dj,c])_k * W[(di,dj,k,c), f]
// feat_k = cubic B-spline basis (k<8) or silu (k==8); W = sk*sf (k<8) or sf.
// Implicit GEMM: M=28800, N=128, K=82 chunks * 32 ch (chunk 81 = zero pad).
// R10: INSTRUMENTATION ROUND — kernels byte-identical to R9; kan_gemm
//      launched 5x (idempotent) to measure its marginal cost:
//      gemm_us ~= (dur - 114.6)/4 - gap.  No optimization changes.
// ---------------------------------------------------------------------------

#define C_IN   32
#define F_OUT  128
#define BATCH  32
#define HIN    32
#define WIN    32
#define HO_    30
#define WO_    30
#define NPIX   (BATCH*HO_*WO_)        // 28800
#define NELEM  (BATCH*HIN*WIN*C_IN)   // 1048576
#define NBASIS 9                      // 8 spline + 1 silu
#define KCHUNKS 82                    // 81 real + 1 zero pad (even pairing)
#define NSUPER 41                     // K super-stages of 2 chunks
#define FEAT_BYTES  ((size_t)NELEM*NBASIS*2)       // 18,874,368
#define WPACK_BYTES ((size_t)KCHUNKS*F_OUT*32*2)   // 671,744 (82 chunks)

typedef __attribute__((ext_vector_type(8))) short short8;   // 8 bf16 = 4 VGPR
typedef __attribute__((ext_vector_type(4))) float f32x4;

__device__ __forceinline__ short bf16_bits(float v) {
  return __builtin_bit_cast(short, __float2bfloat16(v));
}

// async global->LDS, 16B per lane. LDS dest must be linear-in-lane (HW uses
// wave-uniform base + lane*16); our dest = base + tid*16 satisfies this.
#define GLOAD_LDS16(g, l) \
  __builtin_amdgcn_global_load_lds((const __attribute__((address_space(1))) void*)(g), \
                                   (__attribute__((address_space(3))) void*)(l), 16, 0, 0)

// ---------------------------------------------------------------------------
// Kernel A: featurize, 8 elems/thread. feat[bhw][k][c] bf16, 64B per (bhw,k).
// Knots g[j] = -2.2 + 0.4j, j=0..11. Loads 2x float4, stores 9x short8.
// ---------------------------------------------------------------------------
__device__ __forceinline__ void kan_basis(float v, float* o9) {
  float b0[11], b1[10], b2[9];
#pragma unroll
  for (int j = 0; j < 11; ++j) {
    float gj  = -2.2f + 0.4f * (float)j;
    float gj1 = -2.2f + 0.4f * (float)(j + 1);
    b0[j] = (v >= gj && v < gj1) ? 1.0f : 0.0f;
  }
#pragma unroll
  for (int j = 0; j < 10; ++j) {
    float gj = -2.2f + 0.4f * (float)j;
    b1[j] = (v - gj) * 2.5f * b0[j] + ((gj + 0.8f) - v) * 2.5f * b0[j + 1];
  }
#pragma unroll
  for (int j = 0; j < 9; ++j) {
    float gj = -2.2f + 0.4f * (float)j;
    b2[j] = (v - gj) * 1.25f * b1[j] + ((gj + 1.2f) - v) * 1.25f * b1[j + 1];
  }
#pragma unroll
  for (int j = 0; j < 8; ++j) {
    float gj = -2.2f + 0.4f * (float)j;
    o9[j] = (v - gj) * (1.0f/1.2f) * b2[j] + ((gj + 1.6f) - v) * (1.0f/1.2f) * b2[j + 1];
  }
  o9[8] = v / (1.0f + __expf(-v));
}

__global__ __launch_bounds__(256) void kan_featurize(
    const float* __restrict__ x, __hip_bfloat16* __restrict__ feat) {
  int t = blockIdx.x * 256 + threadIdx.x;     // 131072 threads, exact
  int bhw = t >> 2, c0 = (t & 3) * 8;
  const f32x4* xp = (const f32x4*)(x + ((size_t)bhw * 32 + c0));
  f32x4 v0 = xp[0], v1 = xp[1];
  float f[8][9];
#pragma unroll
  for (int j = 0; j < 4; ++j) kan_basis(v0[j], f[j]);
#pragma unroll
  for (int j = 0; j < 4; ++j) kan_basis(v1[j], f[4 + j]);

  char* o = (char*)feat + (size_t)bhw * 576 + c0 * 2;
#pragma unroll
  for (int k = 0; k < 9; ++k) {
    short8 s;
#pragma unroll
    for (int j = 0; j < 8; ++j)
      s[j] = bf16_bits(f[j][k]);
    *(short8*)(o + k * 64) = s;
  }
}

// ---------------------------------------------------------------------------
// Kernel C: pack W -> [kc][col][4 x 16B parts, XOR-swizzled][8 bf16].
// 8 elems/thread: t -> (kc, col, part); csub = part*8+j; i = dd*32+csub.
// Chunk 81 is all-zero padding (even K-pairing in the GEMM).
// Swizzle: part p of col r stored at slot p ^ ((r>>1)&3)  (self-inverse).
// ---------------------------------------------------------------------------
__global__ __launch_bounds__(256) void kan_pack_w(
    const float* __restrict__ sk, const float* __restrict__ sf,
    __hip_bfloat16* __restrict__ wp) {
  int t = blockIdx.x * 256 + threadIdx.x;   // 41984 threads, exact (164 blk)
  int part = t & 3;
  int col  = (t >> 2) & 127;
  int kc   = t >> 9;                        // 0..81
  int dd = kc / 9, k = kc - dd * 9;
  short8 s;
#pragma unroll
  for (int j = 0; j < 8; ++j) {
    float w = 0.0f;
    if (kc < 81) {
      int i = dd * 32 + part * 8 + j;
      w = sf[i * 128 + col];
      if (k < 8) w *= sk[(i * 8 + k) * 128 + col];
    }
    s[j] = bf16_bits(w);
  }
  int slot = part ^ ((col >> 1) & 3);
  *(short8*)((char*)wp + (size_t)kc * 8192 + col * 64 + slot * 16) = s;
}

// ---------------------------------------------------------------------------
// Kernel B: implicit GEMM. 450 blocks x 256 thr (4 waves, 2x2 of 32x64).
// Super-stage = 2 K-chunks (BK=64). Ring: 3 super-stages; per stage
// A 2x4KB at s*8192, B 2x8KB at 24576+s*16384; total 72 KB -> 2 blocks/CU.
// Steady wait vmcnt(6): stage t+1 landed, stage t+2's 6 loads in flight.
// ---------------------------------------------------------------------------
__global__ __launch_bounds__(256) void kan_gemm(
    const __hip_bfloat16* __restrict__ featb, const __hip_bfloat16* __restrict__ wpb,
    const float* __restrict__ kbias, const float* __restrict__ cbias,
    float* __restrict__ out) {
  __shared__ char lds[73728];
  const char* feat = (const char*)featb;
  const char* wp   = (const char*)wpb;

  int tid  = threadIdx.x;
  int lane = tid & 63, wid = tid >> 6;
  int wm = wid >> 1, wn = wid & 1;
  int q = lane >> 4, fr = lane & 15;

  // bijective XCD swizzle (m204): nwg=450=8*56+2 -> xcd 0,1 get 57 blocks.
  int orig = blockIdx.x;
  int xcd = orig & 7, sub = orig >> 3;
  int swz = (xcd < 2 ? xcd * 57 : 114 + (xcd - 2) * 56) + sub;
  int mb = swz * 64;

  // --- A staging source: thread t -> (row=t>>2, slot=t&3); fetch part p s.t.
  //     stored slot holds part p = slot ^ ((row>>1)&3).
  int arow = tid >> 2, aslot = tid & 3;
  int apix = mb + arow;
  int wo = apix % 30, t30 = apix / 30;
  int ho = t30 % 30,  bb  = t30 / 30;
  const char* asrc = feat + (size_t)((bb * 32 + ho) * 32 + wo) * 576
                          + (size_t)((aslot ^ ((arow >> 1) & 3)) * 16);

  // --- fragment LDS byte offsets (swizzled reads)
  int ar0 = 32 * wm + fr, ar1 = ar0 + 16;
  int aoff0 = ar0 * 64 + ((q ^ ((ar0 >> 1) & 3)) * 16);
  int aoff1 = ar1 * 64 + ((q ^ ((ar1 >> 1) & 3)) * 16);
  int boff[4];
#pragma unroll
  for (int n = 0; n < 4; ++n) {
    int col = 64 * wn + 16 * n + fr;
    boff[n] = col * 64 + ((q ^ ((col >> 1) & 3)) * 16);
  }

  f32x4 acc[2][4];
#pragma unroll
  for (int m = 0; m < 2; ++m)
#pragma unroll
    for (int n = 0; n < 4; ++n) acc[m][n] = (f32x4)(0.0f);

  // super-stage t: chunks (2t, 2t+1). 6 global_load_lds per thread.
  auto stage = [&](int t) {
    int s = t % 3;
#pragma unroll
    for (int h = 0; h < 2; ++h) {
      int kc = 2 * t + h;                      // <= 81
      int kcl = kc < 81 ? kc : 80;             // A-addr clamp for pad chunk
      int dd = kcl / 9, k = kcl - dd * 9;      // uniform scalar math
      int di = dd / 3, dj = dd - di * 3;
      int au = (di * 32 + dj) * 576 + k * 64;  // window shift + basis slot
      GLOAD_LDS16(asrc + au, lds + s * 8192 + h * 4096 + tid * 16);
      const char* wsrc = wp + (size_t)kc * 8192 + tid * 16;
      GLOAD_LDS16(wsrc,        lds + 24576 + s * 16384 + h * 8192 + tid * 16);
      GLOAD_LDS16(wsrc + 4096, lds + 24576 + s * 16384 + h * 8192 + 4096 + tid * 16);
    }
  };

  auto compute = [&](int t) {
    int s = t % 3;
    __builtin_amdgcn_s_setprio(1);
#pragma unroll
    for (int h = 0; h < 2; ++h) {
      const char* A = lds + s * 8192 + h * 4096;
      const char* B = lds + 24576 + s * 16384 + h * 8192;
      short8 a0 = *(const short8*)(A + aoff0);
      short8 a1 = *(const short8*)(A + aoff1);
#pragma unroll
      for (int n = 0; n < 4; ++n) {
        short8 bn = *(const short8*)(B + boff[n]);
        acc[0][n] = __builtin_amdgcn_mfma_f32_16x16x32_bf16(a0, bn, acc[0][n], 0, 0, 0);
        acc[1][n] = __builtin_amdgcn_mfma_f32_16x16x32_bf16(a1, bn, acc[1][n], 0, 0, 0);
      }
    }
    __builtin_amdgcn_s_setprio(0);
  };

  // prologue: fill 2 super-stages, wait for stage 0 (stage 1's 6 may fly)
  stage(0); stage(1);
  asm volatile("s_waitcnt vmcnt(6)" ::: "memory");
  __builtin_amdgcn_s_barrier();
  __builtin_amdgcn_sched_barrier(0);

  // main loop: t=0..38 issues stages 2..40. End-of-iter vmcnt(6): stage t+1
  // complete, stage t+2's 6 loads in flight across the barrier.
  for (int t = 0; t < NSUPER - 2; ++t) {
    stage(t + 2);                // overwrites buf (t-1)%3, consumed last iter
    compute(t);
    asm volatile("s_waitcnt vmcnt(6) lgkmcnt(0)" ::: "memory");
    __builtin_amdgcn_s_barrier();
    __builtin_amdgcn_sched_barrier(0);
  }
  // drain: stages 39,40 issued; finish them, then barrier-free tail.
  asm volatile("s_waitcnt vmcnt(0)" ::: "memory");
  __builtin_amdgcn_s_barrier();
  __builtin_amdgcn_sched_barrier(0);
  compute(NSUPER - 2);
  compute(NSUPER - 1);

  // epilogue: C/D mapping col=lane&15, row=(lane>>4)*4+reg  [m89-verified]
#pragma unroll
  for (int n = 0; n < 4; ++n) {
    int col = 64 * wn + 16 * n + fr;
    float bias = kbias[col] + cbias[col];
#pragma unroll
    for (int m = 0; m < 2; ++m) {
      int row = mb + 32 * wm + 16 * m + q * 4;
      f32x4 v = acc[m][n];
#pragma unroll
      for (int r = 0; r < 4; ++r)
        out[(size_t)(row + r) * 128 + col] = v[r] + bias;
    }
  }
}

// ---------------------------------------------------------------------------
extern "C" void kernel_launch(void* const* d_in, const int* in_sizes, int n_in,
                              void* d_out, int out_size, void* d_ws, size_t ws_size,
                              hipStream_t stream) {
  const float* x  = (const float*)d_in[0];
  const float* sk = (const float*)d_in[1];   // (288, 8, 128)
  const float* sf = (const float*)d_in[2];   // (288, 128)
  const float* kb = (const float*)d_in[3];   // (128,)
  const float* cb = (const float*)d_in[4];   // (128,)
  float* out = (float*)d_out;                // (32,30,30,128) f32

  char* ws = (char*)d_ws;
  __hip_bfloat16* feat = (__hip_bfloat16*)ws;                 // 18.9 MB
  __hip_bfloat16* wpk  = (__hip_bfloat16*)(ws + FEAT_BYTES);  // 672 KB (82 ch)

  hipLaunchKernelGGL(kan_featurize, dim3(NELEM / 8 / 256), dim3(256), 0, stream, x, feat);
  hipLaunchKernelGGL(kan_pack_w, dim3((KCHUNKS * F_OUT * 32 / 8) / 256), dim3(256), 0, stream,
                     sk, sf, wpk);
  // INSTRUMENTATION: 5 idempotent GEMM launches. Marginal cost of the
  // extra 4 = 4 x gemm_us. gemm_us ~= (dur - 114.6)/4 - gap(~2).
  hipLaunchKernelGGL(kan_gemm, dim3(NPIX / 64), dim3(256), 0, stream,
                     feat, wpk, kb, cb, out);
  hipLaunchKernelGGL(kan_gemm, dim3(NPIX / 64), dim3(256), 0, stream,
                     feat, wpk, kb, cb, out);
  hipLaunchKernelGGL(kan_gemm, dim3(NPIX / 64), dim3(256), 0, stream,
                     feat, wpk, kb, cb, out);
  hipLaunchKernelGGL(kan_gemm, dim3(NPIX / 64), dim3(256), 0, stream,
                     feat, wpk, kb, cb, out);
  hipLaunchKernelGGL(kan_gemm, dim3(NPIX / 64), dim3(256), 0, stream,
                     feat, wpk, kb, cb, out);
}

// Round 11
// 116.889 us; speedup vs baseline: 1.9031x; 1.9031x over previous
//
#include <hip/hip_runtime.h>
#include <hip/hip_bf16.h>

// ---------------------------------------------------------------------------
// Conv2DKAN: out[b,ho,wo,f] = sum_{di,dj,c,k} feat(x[b,ho+di,wo+dj,c])_k * W[(di,dj,k,c), f]
// feat_k = cubic B-spline basis (k<8) or silu (k==8); W = sk*sf (k<8) or sf.
// Implicit GEMM: M=28800, N=128, K=81 chunks*32 (pad to 84 for prefetch).
// R11: GEMM was LDS-BW-bound (R10 instrumentation: 27us marginal; ~770
//      LDS-cyc/chunk vs 78 MFMA-cyc). New GEMM: B direct global->reg ring
//      (L2-resident, zero LDS), wave tile 64x64 (2-wave 128-thr blocks),
//      A via 3-stage LDS ring. LDS bytes/chunk 3x lower. Producer kernels
//      merged (featurize+pack in one launch).
// ---------------------------------------------------------------------------

#define C_IN   32
#define F_OUT  128
#define BATCH  32
#define NPIX   28800                  // 32*30*30
#define NELEM  1048576                // 32*32*32*32
#define KREAL  81                     // 9 window pos * 9 basis slots
#define KALLOC 84                     // +3 zero pad (prefetch reads t+2)
#define FEAT_BYTES  ((size_t)NELEM*9*2)            // 18,874,368
#define WPACK_BYTES ((size_t)KALLOC*F_OUT*32*2)    // 688,128

typedef __attribute__((ext_vector_type(8))) short short8;   // 8 bf16 = 4 VGPR
typedef __attribute__((ext_vector_type(4))) float f32x4;

__device__ __forceinline__ short bf16_bits(float v) {
  return __builtin_bit_cast(short, __float2bfloat16(v));
}

#define GLOAD_LDS16(g, l) \
  __builtin_amdgcn_global_load_lds((const __attribute__((address_space(1))) void*)(g), \
                                   (__attribute__((address_space(3))) void*)(l), 16, 0, 0)

// ---------------------------------------------------------------------------
// Basis: knots g[j] = -2.2 + 0.4j, j=0..11 (Cox-de Boor, cubic).
// ---------------------------------------------------------------------------
__device__ __forceinline__ void kan_basis(float v, float* o9) {
  float b0[11], b1[10], b2[9];
#pragma unroll
  for (int j = 0; j < 11; ++j) {
    float gj  = -2.2f + 0.4f * (float)j;
    float gj1 = -2.2f + 0.4f * (float)(j + 1);
    b0[j] = (v >= gj && v < gj1) ? 1.0f : 0.0f;
  }
#pragma unroll
  for (int j = 0; j < 10; ++j) {
    float gj = -2.2f + 0.4f * (float)j;
    b1[j] = (v - gj) * 2.5f * b0[j] + ((gj + 0.8f) - v) * 2.5f * b0[j + 1];
  }
#pragma unroll
  for (int j = 0; j < 9; ++j) {
    float gj = -2.2f + 0.4f * (float)j;
    b2[j] = (v - gj) * 1.25f * b1[j] + ((gj + 1.2f) - v) * 1.25f * b1[j + 1];
  }
#pragma unroll
  for (int j = 0; j < 8; ++j) {
    float gj = -2.2f + 0.4f * (float)j;
    o9[j] = (v - gj) * (1.0f/1.2f) * b2[j] + ((gj + 1.6f) - v) * (1.0f/1.2f) * b2[j + 1];
  }
  o9[8] = v / (1.0f + __expf(-v));
}

// ---------------------------------------------------------------------------
// Producer (merged): blocks <512 featurize (8 elems/thread, 16B stores);
// blocks >=512 pack W -> [kc][col][4 parts XOR-swz][8 bf16], kc 81..83 zero.
// ---------------------------------------------------------------------------
__global__ __launch_bounds__(256) void kan_producer(
    const float* __restrict__ x, const float* __restrict__ sk,
    const float* __restrict__ sf, __hip_bfloat16* __restrict__ feat,
    __hip_bfloat16* __restrict__ wp) {
  if (blockIdx.x < 512) {
    int t = blockIdx.x * 256 + threadIdx.x;     // 131072 threads, exact
    int bhw = t >> 2, c0 = (t & 3) * 8;
    const f32x4* xp = (const f32x4*)(x + ((size_t)bhw * 32 + c0));
    f32x4 v0 = xp[0], v1 = xp[1];
    float f[8][9];
#pragma unroll
    for (int j = 0; j < 4; ++j) kan_basis(v0[j], f[j]);
#pragma unroll
    for (int j = 0; j < 4; ++j) kan_basis(v1[j], f[4 + j]);
    char* o = (char*)feat + (size_t)bhw * 576 + c0 * 2;
#pragma unroll
    for (int k = 0; k < 9; ++k) {
      short8 s;
#pragma unroll
      for (int j = 0; j < 8; ++j) s[j] = bf16_bits(f[j][k]);
      *(short8*)(o + k * 64) = s;
    }
  } else {
    int t = (blockIdx.x - 512) * 256 + threadIdx.x;  // 43008 threads, exact
    int part = t & 3;
    int col  = (t >> 2) & 127;
    int kc   = t >> 9;                               // 0..83
    int dd = kc / 9, k = kc - dd * 9;
    short8 s;
#pragma unroll
    for (int j = 0; j < 8; ++j) {
      float w = 0.0f;
      if (kc < KREAL) {
        int i = dd * 32 + part * 8 + j;
        w = sf[i * 128 + col];
        if (k < 8) w *= sk[(i * 8 + k) * 128 + col];
      }
      s[j] = bf16_bits(w);
    }
    int slot = part ^ ((col >> 1) & 3);
    *(short8*)((char*)wp + (size_t)kc * 8192 + col * 64 + slot * 16) = s;
  }
}

// ---------------------------------------------------------------------------
// GEMM: 450 blocks x 128 thr (2 waves; wave tile 64Mx64N, wn=wid).
// A: 3-stage LDS ring (3x4KB), staged 2 ahead via global_load_lds.
// B: direct global->reg, 3-slot ring br[3][4], loaded 2 ahead (L2-resident).
// Per-iter VMEM = 4 B-loads + 2 A-gloads = 6; steady wait vmcnt(6) retires
// through chunk t+1 (issue order ... B(t+1) A(t+1) | B(t+2) A(t+2)).
// One s_barrier/chunk for the shared A ring (2 waves only).
// ---------------------------------------------------------------------------
__global__ __launch_bounds__(128) void kan_gemm(
    const __hip_bfloat16* __restrict__ featb, const __hip_bfloat16* __restrict__ wpb,
    const float* __restrict__ kbias, const float* __restrict__ cbias,
    float* __restrict__ out) {
  __shared__ char lds[12288];
  const char* feat = (const char*)featb;
  const char* wp   = (const char*)wpb;

  int tid  = threadIdx.x;
  int lane = tid & 63, wn = tid >> 6;     // 2 waves: wn = 0,1
  int q = lane >> 4, fr = lane & 15;

  // bijective XCD swizzle (m204): nwg=450=8*56+2 -> xcd 0,1 get 57 blocks.
  int orig = blockIdx.x;
  int xcd = orig & 7, sub = orig >> 3;
  int swz = (xcd < 2 ? xcd * 57 : 114 + (xcd - 2) * 56) + sub;
  int mb = swz * 64;

  // --- A staging sources. Thread t writes LDS bytes {t*16, 2048+t*16} of a
  // 4KB chunk tile -> (row=32j + t>>2, slot=t&3). Stored slot holds part
  // p = slot ^ ((row>>1)&3); rows r and r+32 share p.
  int r0 = tid >> 2;
  int p  = (tid & 3) ^ ((r0 >> 1) & 3);
  int pixa = mb + r0, pixb = mb + 32 + r0;
  int woa = pixa % 30, ta = pixa / 30, hoa = ta % 30, ba = ta / 30;
  int wob = pixb % 30, tb_ = pixb / 30, hob = tb_ % 30, bb = tb_ / 30;
  const char* asrc0 = feat + (size_t)((ba * 32 + hoa) * 32 + woa) * 576 + p * 16;
  const char* asrc1 = feat + (size_t)((bb * 32 + hob) * 32 + wob) * 576 + p * 16;

  // --- A fragment read offsets (within a 4KB slot), m=0..3 (rows 16m+fr)
  int aoff[4];
#pragma unroll
  for (int m = 0; m < 4; ++m) {
    int row = 16 * m + fr;
    aoff[m] = row * 64 + ((q ^ ((row >> 1) & 3)) * 16);
  }

  // --- B read pointer: col = 64*wn + 16*n + fr; swizzle slot depends only on
  // fr ((col>>1)&3 == (fr>>1)&3 since 64wn,16n are multiples of 8 after >>1&3).
  const char* bptr = wp + (size_t)(64 * wn + fr) * 64 + ((q ^ ((fr >> 1) & 3)) * 16);

  f32x4 acc[4][4];
#pragma unroll
  for (int m = 0; m < 4; ++m)
#pragma unroll
    for (int n = 0; n < 4; ++n) acc[m][n] = (f32x4)(0.0f);

  short8 br[3][4];   // B register ring; all indices compile-time (x3 unroll)

#define STAGEA(KC, S) do {                                                   \
    int kc_ = (KC) > 80 ? 80 : (KC);                                         \
    int dd_ = kc_ / 9, kk_ = kc_ - dd_ * 9;                                  \
    int di_ = dd_ / 3, dj_ = dd_ - di_ * 3;                                  \
    int au_ = (di_ * 32 + dj_) * 576 + kk_ * 64;                             \
    GLOAD_LDS16(asrc0 + au_, lds + (S) * 4096 + tid * 16);                   \
    GLOAD_LDS16(asrc1 + au_, lds + (S) * 4096 + 2048 + tid * 16);            \
  } while (0)

#define LOADB(KC, S) do {                                                    \
    _Pragma("unroll")                                                        \
    for (int n = 0; n < 4; ++n)                                              \
      br[S][n] = *(const short8*)(bptr + (size_t)(KC) * 8192 + n * 1024);    \
  } while (0)

#define GBODY(T, S0, S1, S2) do {                                            \
    LOADB((T) + 2, S2);                                                      \
    STAGEA((T) + 2, S2);                                                     \
    __builtin_amdgcn_s_setprio(1);                                           \
    _Pragma("unroll")                                                        \
    for (int m = 0; m < 4; ++m) {                                            \
      short8 am = *(const short8*)(lds + (S0) * 4096 + aoff[m]);             \
      _Pragma("unroll")                                                      \
      for (int n = 0; n < 4; ++n)                                            \
        acc[m][n] = __builtin_amdgcn_mfma_f32_16x16x32_bf16(                 \
            am, br[S0][n], acc[m][n], 0, 0, 0);                              \
    }                                                                        \
    __builtin_amdgcn_s_setprio(0);                                           \
    asm volatile("s_waitcnt vmcnt(6) lgkmcnt(0)" ::: "memory");              \
    __builtin_amdgcn_s_barrier();                                            \
    __builtin_amdgcn_sched_barrier(0);                                       \
  } while (0)

  // prologue: A0->slot0, A1->slot1, B0->br0, B1->br1.
  // issue order A0(2) A1(2) B0(4) B1(4); vmcnt(4) retires through B0.
  STAGEA(0, 0);
  STAGEA(1, 1);
  LOADB(0, 0);
  LOADB(1, 1);
  asm volatile("s_waitcnt vmcnt(4)" ::: "memory");
  __builtin_amdgcn_s_barrier();
  __builtin_amdgcn_sched_barrier(0);

  // main: 81 chunks = 27 x 3 (static ring indices)
  for (int tb = 0; tb < 27; ++tb) {
    int t0 = 3 * tb;
    GBODY(t0,     0, 1, 2);
    GBODY(t0 + 1, 1, 2, 0);
    GBODY(t0 + 2, 2, 0, 1);
  }

  // epilogue: C/D mapping col=lane&15, row=(lane>>4)*4+reg  [m89-verified]
#pragma unroll
  for (int n = 0; n < 4; ++n) {
    int col = 64 * wn + 16 * n + fr;
    float bias = kbias[col] + cbias[col];
#pragma unroll
    for (int m = 0; m < 4; ++m) {
      int row = mb + 16 * m + q * 4;
      f32x4 v = acc[m][n];
#pragma unroll
      for (int r = 0; r < 4; ++r)
        out[(size_t)(row + r) * 128 + col] = v[r] + bias;
    }
  }
#undef GBODY
#undef LOADB
#undef STAGEA
}

// ---------------------------------------------------------------------------
extern "C" void kernel_launch(void* const* d_in, const int* in_sizes, int n_in,
                              void* d_out, int out_size, void* d_ws, size_t ws_size,
                              hipStream_t stream) {
  const float* x  = (const float*)d_in[0];
  const float* sk = (const float*)d_in[1];   // (288, 8, 128)
  const float* sf = (const float*)d_in[2];   // (288, 128)
  const float* kb = (const float*)d_in[3];   // (128,)
  const float* cb = (const float*)d_in[4];   // (128,)
  float* out = (float*)d_out;                // (32,30,30,128) f32

  char* ws = (char*)d_ws;
  __hip_bfloat16* feat = (__hip_bfloat16*)ws;                 // 18.9 MB
  __hip_bfloat16* wpk  = (__hip_bfloat16*)(ws + FEAT_BYTES);  // 688 KB (84 ch)

  hipLaunchKernelGGL(kan_producer, dim3(512 + 168), dim3(256), 0, stream,
                     x, sk, sf, feat, wpk);
  hipLaunchKernelGGL(kan_gemm, dim3(NPIX / 64), dim3(128), 0, stream,
                     feat, wpk, kb, cb, out);
}